// Round 1
// baseline (151.898 us; speedup 1.0000x reference)
//
#include <hip/hip_runtime.h>

#define T_MAX 1024
#define N_NODES 512
#define FEAT 512
#define BATCH_B 4

__global__ __launch_bounds__(128) void node_embed_kernel(
    const int* __restrict__ tokens,        // [B, T]
    const int* __restrict__ starts,        // [B, N]
    const int* __restrict__ ends,          // [B, N]
    const float* __restrict__ embed_tok,   // [VOCAB, F]
    const float* __restrict__ embed_node,  // [N, F]
    const float* __restrict__ pos_emb,     // [1, T, F]
    float* __restrict__ out)               // [B, T, F]
{
    const int bt  = blockIdx.x;       // 0 .. B*T-1
    const int b   = bt >> 10;         // / 1024
    const int t   = bt & (T_MAX - 1);
    const int tid = threadIdx.x;      // 0..127, each owns 4 floats of F

    // Stage span tables for this batch in LDS (4 KB).
    __shared__ int ss[N_NODES];
    __shared__ int se[N_NODES];
    const int* __restrict__ sb = starts + b * N_NODES;
    const int* __restrict__ eb = ends   + b * N_NODES;
    for (int n = tid; n < N_NODES; n += 128) {
        ss[n] = sb[n];
        se[n] = eb[n];
    }
    __syncthreads();

    const int tok = tokens[b * T_MAX + t];
    const int f4  = tid * 4;

    float4 acc = *reinterpret_cast<const float4*>(embed_tok + (size_t)tok * FEAT + f4);
    const float4 pe = *reinterpret_cast<const float4*>(pos_emb + (size_t)t * FEAT + f4);
    acc.x += pe.x; acc.y += pe.y; acc.z += pe.z; acc.w += pe.w;

    // Scan all nodes; condition is block-uniform (depends only on t), so the
    // branch is divergence-free and skipped iterations cost ~nothing.
    // Deterministic ascending-n order => bitwise-stable output.
    for (int n = 0; n < N_NODES; ++n) {
        if (ss[n] <= t && t <= se[n]) {
            const float4 nv =
                *reinterpret_cast<const float4*>(embed_node + (size_t)n * FEAT + f4);
            acc.x += nv.x; acc.y += nv.y; acc.z += nv.z; acc.w += nv.w;
        }
    }

    *reinterpret_cast<float4*>(out + (size_t)bt * FEAT + f4) = acc;
}

extern "C" void kernel_launch(void* const* d_in, const int* in_sizes, int n_in,
                              void* d_out, int out_size, void* d_ws, size_t ws_size,
                              hipStream_t stream) {
    const int*   tokens     = (const int*)d_in[0];
    const int*   starts     = (const int*)d_in[1];
    const int*   ends       = (const int*)d_in[2];
    const float* embed_tok  = (const float*)d_in[3];
    const float* embed_node = (const float*)d_in[4];
    const float* pos_emb    = (const float*)d_in[5];
    float*       out        = (float*)d_out;

    node_embed_kernel<<<dim3(BATCH_B * T_MAX), dim3(128), 0, stream>>>(
        tokens, starts, ends, embed_tok, embed_node, pos_emb, out);
}

// Round 3
// 104.400 us; speedup vs baseline: 1.4550x; 1.4550x over previous
//
#include <hip/hip_runtime.h>

#define T_MAX 1024
#define N_NODES 512
#define FEAT 512
#define BATCH_B 4
#define WAVES_PER_BLOCK 4

// One wave (64 lanes) per (b, t). Lane l owns features [l*4, l*4+4) and
// [256 + l*4, 256 + l*4 + 4) -> two fully-coalesced float4 streams.
// Span scan: 8 ballot rounds (64 nodes each); matched nodes walked in
// ascending order from the wave-uniform ballot mask (no atomics, no LDS).
__global__ __launch_bounds__(256) void node_embed_kernel(
    const int* __restrict__ tokens,        // [B*T]
    const int* __restrict__ starts,        // [B*N]
    const int* __restrict__ ends,          // [B*N]
    const float* __restrict__ embed_tok,   // [VOCAB, F]
    const float* __restrict__ embed_node,  // [N, F]
    const float* __restrict__ pos_emb,     // [T, F]
    float* __restrict__ out)               // [B*T, F]
{
    const int wave = threadIdx.x >> 6;
    const int lane = threadIdx.x & 63;
    const int bt   = blockIdx.x * WAVES_PER_BLOCK + wave;  // 0 .. B*T-1
    const int b    = bt >> 10;
    const int t    = bt & (T_MAX - 1);

    const int tok = tokens[bt];
    const int f0  = lane * 4;
    const int f1  = 256 + lane * 4;

    const float* trow = embed_tok + (size_t)tok * FEAT;
    const float* prow = pos_emb + (size_t)t * FEAT;

    float4 acc0 = *reinterpret_cast<const float4*>(trow + f0);
    float4 acc1 = *reinterpret_cast<const float4*>(trow + f1);
    const float4 p0 = *reinterpret_cast<const float4*>(prow + f0);
    const float4 p1 = *reinterpret_cast<const float4*>(prow + f1);
    acc0.x += p0.x; acc0.y += p0.y; acc0.z += p0.z; acc0.w += p0.w;
    acc1.x += p1.x; acc1.y += p1.y; acc1.z += p1.z; acc1.w += p1.w;

    const int* __restrict__ sb = starts + b * N_NODES;
    const int* __restrict__ eb = ends   + b * N_NODES;

    #pragma unroll
    for (int r = 0; r < N_NODES / 64; ++r) {
        const int n = (r << 6) + lane;
        const int s = sb[n];
        const int e = eb[n];
        unsigned long long m = __ballot(s <= t && t <= e);
        // Wave-uniform mask: all lanes walk the same bits, ascending n.
        while (m) {
            const int bit = __builtin_ctzll(m);
            m &= m - 1;
            const float* nrow = embed_node + (size_t)((r << 6) + bit) * FEAT;
            const float4 v0 = *reinterpret_cast<const float4*>(nrow + f0);
            const float4 v1 = *reinterpret_cast<const float4*>(nrow + f1);
            acc0.x += v0.x; acc0.y += v0.y; acc0.z += v0.z; acc0.w += v0.w;
            acc1.x += v1.x; acc1.y += v1.y; acc1.z += v1.z; acc1.w += v1.w;
        }
    }

    float* orow = out + (size_t)bt * FEAT;
    *reinterpret_cast<float4*>(orow + f0) = acc0;
    *reinterpret_cast<float4*>(orow + f1) = acc1;
}

extern "C" void kernel_launch(void* const* d_in, const int* in_sizes, int n_in,
                              void* d_out, int out_size, void* d_ws, size_t ws_size,
                              hipStream_t stream) {
    const int*   tokens     = (const int*)d_in[0];
    const int*   starts     = (const int*)d_in[1];
    const int*   ends       = (const int*)d_in[2];
    const float* embed_tok  = (const float*)d_in[3];
    const float* embed_node = (const float*)d_in[4];
    const float* pos_emb    = (const float*)d_in[5];
    float*       out        = (float*)d_out;

    node_embed_kernel<<<dim3(BATCH_B * T_MAX / WAVES_PER_BLOCK), dim3(256), 0, stream>>>(
        tokens, starts, ends, embed_tok, embed_node, pos_emb, out);
}